// Round 5
// baseline (177.743 us; speedup 1.0000x reference)
//
#include <hip/hip_runtime.h>

#define LSZ 1024
#define EPS 1e-8f
#define NBLK 2048
#define SPT 2                      // sites per thread; NBLK*256*SPT == L*L exactly
#define STRIDE (NBLK * 256)       // 524288 threads

struct c32 { float re, im; };

__device__ __forceinline__ c32 cmul(c32 a, c32 b) {
    return { a.re * b.re - a.im * b.im, a.re * b.im + a.im * b.re };
}
// a * conj(b)
__device__ __forceinline__ c32 cmulc(c32 a, c32 b) {
    return { a.re * b.re + a.im * b.im, a.im * b.re - a.re * b.im };
}
__device__ __forceinline__ c32 cadd(c32 a, c32 b) {
    return { a.re + b.re, a.im + b.im };
}

// g = cos(n) I + i sinc(n) (theta . sigma). Native sin/cos/rcp: theta norms
// are <= ~7 (3 gaussians), safely in fast range; error ~1e-6 << 8e-2 thresh.
__device__ __forceinline__ void make_g(float tx, float ty, float tz, c32 g[2][2]) {
    float n2 = tx * tx + ty * ty + tz * tz;
    float n  = __builtin_amdgcn_sqrtf(n2);
    float cc = __cosf(n);
    float sn = __sinf(n);
    float s  = (n > EPS) ? (sn * __builtin_amdgcn_rcpf(n)) : 1.0f;
    float a1 = s * tx, a2 = s * ty, a3 = s * tz;
    g[0][0] = {  cc,  a3 };
    g[0][1] = {  a2,  a1 };
    g[1][0] = { -a2,  a1 };
    g[1][1] = {  cc, -a3 };
}

// Ut = g @ M @ gn^dagger ; return sum |P - Ut|^2 over the 4 entries
__device__ __forceinline__ float site_mu_loss(const c32 g[2][2], const c32 gn[2][2],
                                              float4 m0, float4 m1,
                                              float4 p0, float4 p1) {
    c32 M[2][2] = { { { m0.x, m0.y }, { m0.z, m0.w } },
                    { { m1.x, m1.y }, { m1.z, m1.w } } };
    c32 P[2][2] = { { { p0.x, p0.y }, { p0.z, p0.w } },
                    { { p1.x, p1.y }, { p1.z, p1.w } } };
    c32 T[2][2];
#pragma unroll
    for (int a = 0; a < 2; ++a)
#pragma unroll
        for (int cc = 0; cc < 2; ++cc)
            T[a][cc] = cadd(cmul(g[a][0], M[0][cc]), cmul(g[a][1], M[1][cc]));

    float acc = 0.0f;
#pragma unroll
    for (int a = 0; a < 2; ++a)
#pragma unroll
        for (int d = 0; d < 2; ++d) {
            c32 ut = cadd(cmulc(T[a][0], gn[d][0]), cmulc(T[a][1], gn[d][1]));
            float dr = P[a][d].re - ut.re;
            float di = P[a][d].im - ut.im;
            acc += dr * dr + di * di;
        }
    return acc;
}

__device__ __forceinline__ float site_loss(int idx,
                                           const float* __restrict__ theta,
                                           const float* __restrict__ U_pred,
                                           const float* __restrict__ U_true) {
    int x = idx >> 10, y = idx & (LSZ - 1);
    int xp = (x + 1) & (LSZ - 1), yp = (y + 1) & (LSZ - 1);

    const float* ta = theta + 3 * (x  * LSZ + y);
    const float* tb = theta + 3 * (xp * LSZ + y);
    const float* tc = theta + 3 * (x  * LSZ + yp);
    const float4* Ut4 = (const float4*)U_true + (size_t)idx * 4;
    const float4* Up4 = (const float4*)U_pred + (size_t)idx * 4;

    float a0 = ta[0], a1 = ta[1], a2 = ta[2];
    float b0 = tb[0], b1 = tb[1], b2 = tb[2];
    float c0 = tc[0], c1 = tc[1], c2 = tc[2];
    float4 t0 = Ut4[0], t1 = Ut4[1];
    float4 p0 = Up4[0], p1 = Up4[1];

    c32 g[2][2], gn[2][2];
    make_g(a0, a1, a2, g);
    make_g(b0, b1, b2, gn);
    float acc = site_mu_loss(g, gn, t0, t1, p0, p1);   // mu = 0

    float4 t2 = Ut4[2], t3 = Ut4[3];
    float4 p2 = Up4[2], p3 = Up4[3];
    make_g(c0, c1, c2, gn);
    acc += site_mu_loss(g, gn, t2, t3, p2, p3);        // mu = 1
    return acc;
}

// DISAMBIGUATION PROBE (R5). R4 proved probe+gauge both ran <41.3 us (neither
// appeared above the 41-us poison fills) -- i.e. gauge dropped from its
// 4-round-invariant ~49 us when a streaming pre-read ran first. This 3-pass
// version is deliberately >41.3 us so it SHOWS in the top-5 with FETCH_SIZE:
//   pass 1 = cold read of U_pred+U_true (+theta)  -> cold stream rate
//   pass 2,3 = warm re-reads                      -> warm (L3) stream rate
// FETCH_SIZE ~= cold-pass bytes; (dur - cold)/2 = warm-pass time. gauge below
// is bit-identical to R1, so: G = dur_us - 155.6 + 49 - P gives warm-gauge.
// Decision: G<=38 & warm-pass<=22 -> attack gauge's warm-path overhead.
//           G ~= 49 -> warmth is null; 49 is dispatch-intrinsic; roofline.
// partial[] is fully overwritten by gauge afterwards -> output unaffected.
__global__ __launch_bounds__(256) void stream_probe3_kernel(
    const float4* __restrict__ A,
    const float4* __restrict__ B,
    const float2* __restrict__ Th,
    float* __restrict__ partial) {
    const int tid = blockIdx.x * 256 + threadIdx.x;

    float acc = 0.0f;
#pragma unroll 1
    for (int pass = 0; pass < 3; ++pass) {
#pragma unroll
        for (int i = 0; i < 8; ++i) {              // 8 x 16 B x 2 arrays = 256 B/thread
            float4 a = A[(size_t)i * STRIDE + tid];
            float4 b = B[(size_t)i * STRIDE + tid];
            acc += a.x + a.y + a.z + a.w + b.x + b.y + b.z + b.w;
        }
        if (pass == 0) {
#pragma unroll
            for (int j = 0; j < 3; ++j) {          // theta: 3M floats = 3 float2/thread
                float2 t = Th[(size_t)j * STRIDE + tid];
                acc += t.x + t.y;
            }
        }
        // force re-load next pass (no CSE across passes) + keep pass order
        asm volatile("" ::: "memory");
    }

#pragma unroll
    for (int off = 32; off > 0; off >>= 1)
        acc += __shfl_down(acc, off, 64);

    __shared__ float wave_sums[4];
    int lane = threadIdx.x & 63;
    int wave = threadIdx.x >> 6;
    if (lane == 0) wave_sums[wave] = acc;
    __syncthreads();
    if (threadIdx.x == 0)
        partial[blockIdx.x] = wave_sums[0] + wave_sums[1] + wave_sums[2] + wave_sums[3];
}

__global__ __launch_bounds__(256, 8) void gauge_loss_kernel(
    const float* __restrict__ theta,
    const float* __restrict__ U_pred,
    const float* __restrict__ U_true,
    float* __restrict__ partial) {
    const int tid = blockIdx.x * 256 + threadIdx.x;

    float acc = 0.0f;
#pragma unroll
    for (int s = 0; s < SPT; ++s)
        acc += site_loss(tid + s * STRIDE, theta, U_pred, U_true);

    // fold: mean over 4 entries (1/4) and final /(L*L*2)
    acc *= (1.0f / (8.0f * (float)LSZ * (float)LSZ));

    // wave (64-lane) shuffle reduction
#pragma unroll
    for (int off = 32; off > 0; off >>= 1)
        acc += __shfl_down(acc, off, 64);

    __shared__ float wave_sums[4];
    int lane = threadIdx.x & 63;
    int wave = threadIdx.x >> 6;
    if (lane == 0) wave_sums[wave] = acc;
    __syncthreads();
    if (threadIdx.x == 0)
        partial[blockIdx.x] = wave_sums[0] + wave_sums[1] + wave_sums[2] + wave_sums[3];
}

__global__ __launch_bounds__(256) void reduce_kernel(const float* __restrict__ partial,
                                                     float* __restrict__ out) {
    float s = 0.0f;
#pragma unroll
    for (int i = 0; i < NBLK / 256; ++i)
        s += partial[i * 256 + threadIdx.x];

#pragma unroll
    for (int off = 32; off > 0; off >>= 1)
        s += __shfl_down(s, off, 64);

    __shared__ float wave_sums[4];
    int lane = threadIdx.x & 63;
    int wave = threadIdx.x >> 6;
    if (lane == 0) wave_sums[wave] = s;
    __syncthreads();
    if (threadIdx.x == 0)
        out[0] = wave_sums[0] + wave_sums[1] + wave_sums[2] + wave_sums[3];
}

extern "C" void kernel_launch(void* const* d_in, const int* in_sizes, int n_in,
                              void* d_out, int out_size, void* d_ws, size_t ws_size,
                              hipStream_t stream) {
    const float* theta  = (const float*)d_in[0];
    const float* U_pred = (const float*)d_in[1];
    const float* U_true = (const float*)d_in[2];
    float* out = (float*)d_out;
    float* partial = (float*)d_ws;  // NBLK floats

    // 3-pass probe first (measurement + warms U and theta);
    // its partial[] values are fully overwritten by gauge_loss.
    stream_probe3_kernel<<<NBLK, 256, 0, stream>>>((const float4*)U_pred,
                                                   (const float4*)U_true,
                                                   (const float2*)theta, partial);
    gauge_loss_kernel<<<NBLK, 256, 0, stream>>>(theta, U_pred, U_true, partial);
    reduce_kernel<<<1, 256, 0, stream>>>(partial, out);
}

// Round 6
// 164.652 us; speedup vs baseline: 1.0795x; 1.0795x over previous
//
#include <hip/hip_runtime.h>

#define LSZ 1024
#define EPS 1e-8f
#define NBLK 2048
#define SPT 2                      // sites per thread; NBLK*256*SPT == L*L exactly
#define STRIDE (NBLK * 256)       // 524288 threads

typedef float vfloat4 __attribute__((ext_vector_type(4)));

struct c32 { float re, im; };

__device__ __forceinline__ c32 cmul(c32 a, c32 b) {
    return { a.re * b.re - a.im * b.im, a.re * b.im + a.im * b.re };
}
// a * conj(b)
__device__ __forceinline__ c32 cmulc(c32 a, c32 b) {
    return { a.re * b.re + a.im * b.im, a.im * b.re - a.re * b.im };
}
__device__ __forceinline__ c32 cadd(c32 a, c32 b) {
    return { a.re + b.re, a.im + b.im };
}

// g = cos(n) I + i sinc(n) (theta . sigma). Native sin/cos/rcp: theta norms
// are <= ~7 (3 gaussians), safely in fast range; error ~1e-6 << 8e-2 thresh.
__device__ __forceinline__ void make_g(float tx, float ty, float tz, c32 g[2][2]) {
    float n2 = tx * tx + ty * ty + tz * tz;
    float n  = __builtin_amdgcn_sqrtf(n2);
    float cc = __cosf(n);
    float sn = __sinf(n);
    float s  = (n > EPS) ? (sn * __builtin_amdgcn_rcpf(n)) : 1.0f;
    float a1 = s * tx, a2 = s * ty, a3 = s * tz;
    g[0][0] = {  cc,  a3 };
    g[0][1] = {  a2,  a1 };
    g[1][0] = { -a2,  a1 };
    g[1][1] = {  cc, -a3 };
}

// Ut = g @ M @ gn^dagger ; return sum |P - Ut|^2 over the 4 entries
__device__ __forceinline__ float site_mu_loss(const c32 g[2][2], const c32 gn[2][2],
                                              vfloat4 m0, vfloat4 m1,
                                              vfloat4 p0, vfloat4 p1) {
    c32 M[2][2] = { { { m0.x, m0.y }, { m0.z, m0.w } },
                    { { m1.x, m1.y }, { m1.z, m1.w } } };
    c32 P[2][2] = { { { p0.x, p0.y }, { p0.z, p0.w } },
                    { { p1.x, p1.y }, { p1.z, p1.w } } };
    c32 T[2][2];
#pragma unroll
    for (int a = 0; a < 2; ++a)
#pragma unroll
        for (int cc = 0; cc < 2; ++cc)
            T[a][cc] = cadd(cmul(g[a][0], M[0][cc]), cmul(g[a][1], M[1][cc]));

    float acc = 0.0f;
#pragma unroll
    for (int a = 0; a < 2; ++a)
#pragma unroll
        for (int d = 0; d < 2; ++d) {
            c32 ut = cadd(cmulc(T[a][0], gn[d][0]), cmulc(T[a][1], gn[d][1]));
            float dr = P[a][d].re - ut.re;
            float di = P[a][d].im - ut.im;
            acc += dr * dr + di * di;
        }
    return acc;
}

// NT-LOAD variant (R6). R5's split measurement: gauge's WORK is ~19 us (warm
// L3); the invariant ~49 us is first-reader-after-reset service: FETCH 78 MB +
// WRITE 65 MB in 49 us = 2.9 TB/s mixed. The 65 MB of writes in a kernel that
// stores 8 KB = demand writeback of DIRTY poison-fill lines our input misses
// evict; read/write turnaround thrash halves effective read BW. Fix: read
// inputs with __builtin_nontemporal_load (global_load ... nt) -> no cache
// allocation -> no dirty-line eviction -> no writeback interleave; 140 MB
// streams at pure-read rate. Tell: WRITE_SIZE must collapse to ~0.
__device__ __forceinline__ float site_loss(int idx,
                                           const float* __restrict__ theta,
                                           const float* __restrict__ U_pred,
                                           const float* __restrict__ U_true) {
    int x = idx >> 10, y = idx & (LSZ - 1);
    int xp = (x + 1) & (LSZ - 1), yp = (y + 1) & (LSZ - 1);

    const float* ta = theta + 3 * (x  * LSZ + y);
    const float* tb = theta + 3 * (xp * LSZ + y);
    const float* tc = theta + 3 * (x  * LSZ + yp);
    const vfloat4* Ut4 = (const vfloat4*)U_true + (size_t)idx * 4;
    const vfloat4* Up4 = (const vfloat4*)U_pred + (size_t)idx * 4;

    float a0 = __builtin_nontemporal_load(ta);
    float a1 = __builtin_nontemporal_load(ta + 1);
    float a2 = __builtin_nontemporal_load(ta + 2);
    float b0 = __builtin_nontemporal_load(tb);
    float b1 = __builtin_nontemporal_load(tb + 1);
    float b2 = __builtin_nontemporal_load(tb + 2);
    float c0 = __builtin_nontemporal_load(tc);
    float c1 = __builtin_nontemporal_load(tc + 1);
    float c2 = __builtin_nontemporal_load(tc + 2);
    vfloat4 t0 = __builtin_nontemporal_load(Ut4);
    vfloat4 t1 = __builtin_nontemporal_load(Ut4 + 1);
    vfloat4 p0 = __builtin_nontemporal_load(Up4);
    vfloat4 p1 = __builtin_nontemporal_load(Up4 + 1);

    c32 g[2][2], gn[2][2];
    make_g(a0, a1, a2, g);
    make_g(b0, b1, b2, gn);
    float acc = site_mu_loss(g, gn, t0, t1, p0, p1);   // mu = 0

    vfloat4 t2 = __builtin_nontemporal_load(Ut4 + 2);
    vfloat4 t3 = __builtin_nontemporal_load(Ut4 + 3);
    vfloat4 p2 = __builtin_nontemporal_load(Up4 + 2);
    vfloat4 p3 = __builtin_nontemporal_load(Up4 + 3);
    make_g(c0, c1, c2, gn);
    acc += site_mu_loss(g, gn, t2, t3, p2, p3);        // mu = 1
    return acc;
}

__global__ __launch_bounds__(256, 8) void gauge_loss_kernel(
    const float* __restrict__ theta,
    const float* __restrict__ U_pred,
    const float* __restrict__ U_true,
    float* __restrict__ partial) {
    const int tid = blockIdx.x * 256 + threadIdx.x;

    float acc = 0.0f;
#pragma unroll
    for (int s = 0; s < SPT; ++s)
        acc += site_loss(tid + s * STRIDE, theta, U_pred, U_true);

    // fold: mean over 4 entries (1/4) and final /(L*L*2)
    acc *= (1.0f / (8.0f * (float)LSZ * (float)LSZ));

    // wave (64-lane) shuffle reduction
#pragma unroll
    for (int off = 32; off > 0; off >>= 1)
        acc += __shfl_down(acc, off, 64);

    __shared__ float wave_sums[4];
    int lane = threadIdx.x & 63;
    int wave = threadIdx.x >> 6;
    if (lane == 0) wave_sums[wave] = acc;
    __syncthreads();
    if (threadIdx.x == 0)
        partial[blockIdx.x] = wave_sums[0] + wave_sums[1] + wave_sums[2] + wave_sums[3];
}

__global__ __launch_bounds__(256) void reduce_kernel(const float* __restrict__ partial,
                                                     float* __restrict__ out) {
    float s = 0.0f;
#pragma unroll
    for (int i = 0; i < NBLK / 256; ++i)
        s += partial[i * 256 + threadIdx.x];

#pragma unroll
    for (int off = 32; off > 0; off >>= 1)
        s += __shfl_down(s, off, 64);

    __shared__ float wave_sums[4];
    int lane = threadIdx.x & 63;
    int wave = threadIdx.x >> 6;
    if (lane == 0) wave_sums[wave] = s;
    __syncthreads();
    if (threadIdx.x == 0)
        out[0] = wave_sums[0] + wave_sums[1] + wave_sums[2] + wave_sums[3];
}

extern "C" void kernel_launch(void* const* d_in, const int* in_sizes, int n_in,
                              void* d_out, int out_size, void* d_ws, size_t ws_size,
                              hipStream_t stream) {
    const float* theta  = (const float*)d_in[0];
    const float* U_pred = (const float*)d_in[1];
    const float* U_true = (const float*)d_in[2];
    float* out = (float*)d_out;
    float* partial = (float*)d_ws;  // NBLK floats

    gauge_loss_kernel<<<NBLK, 256, 0, stream>>>(theta, U_pred, U_true, partial);
    reduce_kernel<<<1, 256, 0, stream>>>(partial, out);
}

// Round 7
// 159.368 us; speedup vs baseline: 1.1153x; 1.0332x over previous
//
#include <hip/hip_runtime.h>

#define LSZ 1024
#define EPS 1e-8f
#define NBLK 512
#define SPT 8                       // phases per thread; NBLK*256*SPT == L*L exactly
#define TSTRIDE (NBLK * 256)        // 131072 threads

typedef float vfloat4 __attribute__((ext_vector_type(4)));

#define AS1 __attribute__((address_space(1)))
#define AS3 __attribute__((address_space(3)))

struct c32 { float re, im; };

__device__ __forceinline__ c32 cmul(c32 a, c32 b) {
    return { a.re * b.re - a.im * b.im, a.re * b.im + a.im * b.re };
}
// a * conj(b)
__device__ __forceinline__ c32 cmulc(c32 a, c32 b) {
    return { a.re * b.re + a.im * b.im, a.im * b.re - a.re * b.im };
}
__device__ __forceinline__ c32 cadd(c32 a, c32 b) {
    return { a.re + b.re, a.im + b.im };
}

// g = cos(n) I + i sinc(n) (theta . sigma). Native sin/cos/rcp: theta norms
// are <= ~7 (3 gaussians), safely in fast range; error ~1e-6 << 8e-2 thresh.
__device__ __forceinline__ void make_g(float tx, float ty, float tz, c32 g[2][2]) {
    float n2 = tx * tx + ty * ty + tz * tz;
    float n  = __builtin_amdgcn_sqrtf(n2);
    float cc = __cosf(n);
    float sn = __sinf(n);
    float s  = (n > EPS) ? (sn * __builtin_amdgcn_rcpf(n)) : 1.0f;
    float a1 = s * tx, a2 = s * ty, a3 = s * tz;
    g[0][0] = {  cc,  a3 };
    g[0][1] = {  a2,  a1 };
    g[1][0] = { -a2,  a1 };
    g[1][1] = {  cc, -a3 };
}

// Ut = g @ M @ gn^dagger ; return sum |P - Ut|^2 over the 4 entries
__device__ __forceinline__ float site_mu_loss(const c32 g[2][2], const c32 gn[2][2],
                                              vfloat4 m0, vfloat4 m1,
                                              vfloat4 p0, vfloat4 p1) {
    c32 M[2][2] = { { { m0.x, m0.y }, { m0.z, m0.w } },
                    { { m1.x, m1.y }, { m1.z, m1.w } } };
    c32 P[2][2] = { { { p0.x, p0.y }, { p0.z, p0.w } },
                    { { p1.x, p1.y }, { p1.z, p1.w } } };
    c32 T[2][2];
#pragma unroll
    for (int a = 0; a < 2; ++a)
#pragma unroll
        for (int cc = 0; cc < 2; ++cc)
            T[a][cc] = cadd(cmul(g[a][0], M[0][cc]), cmul(g[a][1], M[1][cc]));

    float acc = 0.0f;
#pragma unroll
    for (int a = 0; a < 2; ++a)
#pragma unroll
        for (int d = 0; d < 2; ++d) {
            c32 ut = cadd(cmulc(T[a][0], gn[d][0]), cmulc(T[a][1], gn[d][1]));
            float dr = P[a][d].re - ut.re;
            float di = P[a][d].im - ut.im;
            acc += dr * dr + di * di;
        }
    return acc;
}

// DMA-MLP variant (R7). Seven rounds of evidence: warm reads run 7+ TB/s, cold
// HBM reads pin at 2.4 TB/s in EVERY kernel shape -- and every shape had
// VGPR_Count 28-36 (compiler sinks loads; a wave never has >~0.5 KB in
// flight; 17 loads = 41 dwords cannot be live in 32 regs, so R2's fences were
// physically impossible to honor). global_load_lds needs ZERO result VGPRs:
// issue depth is vmcnt-limited (63). Per wave: stage 64 sites x 128 B (U_true
// + U_pred, 8 KB) via 8 gload_lds_dwordx4, double-buffered; counted vmcnt(8)
// keeps the next phase's 8 KB in flight through the whole compute phase.
// 8 waves/CU x 8 KB = 64 KB/CU in flight ~= 3x the 900ns x 23GB/s product.
//
// gload_lds writes LINEAR (base + lane*16, rule #21), so the bank swizzle is
// applied on the GLOBAL source: involution f(c) = c ^ ((c>>3)&7) on 16B-chunk
// index. Writer lane l (instr k) fetches chunk 64k + f(l) -> slot 64k+l holds
// chunk f(64k+l). Reader (thread t, quarter q) wants chunk c=4t+q -> slot
// f(c). Read residues mod 8 are uniform (8 lanes/bank-quad = ds_read_b128
// conflict-free floor). Verified: slot9 holds chunk 8; lane2/q0 reads slot 9.
__global__ __launch_bounds__(256, 2) void gauge_loss_kernel(
    const float* __restrict__ theta,
    const float* __restrict__ U_pred,
    const float* __restrict__ U_true,
    float* __restrict__ partial) {
    // [wave][buf][arr: 0=U_true 1=U_pred][1024 floats = 4 KB]  -> 64 KB total
    __shared__ __align__(16) float lds[4][2][2][1024];
    const int tid  = blockIdx.x * 256 + threadIdx.x;
    const int lane = threadIdx.x & 63;
    const int wv   = threadIdx.x >> 6;
    const int lswz = lane ^ ((lane >> 3) & 7);          // writer-side source swizzle

    // ---- stage: issue 8 global_load_lds (4 KB U_true + 4 KB U_pred) ----
    auto STAGE = [&](int p, int b) {
        const size_t wbase = (size_t)(tid - lane) + (size_t)p * TSTRIDE;
        const char* gT = (const char*)U_true + wbase * 64;
        const char* gP = (const char*)U_pred + wbase * 64;
#pragma unroll
        for (int k = 0; k < 4; ++k) {
            const int c = k * 64 + lswz;                // chunk this lane fetches
            __builtin_amdgcn_global_load_lds(
                (const AS1 void*)(gT + (size_t)c * 16),
                (AS3 void*)((char*)&lds[wv][b][0][0] + k * 1024), 16, 0, 0);
            __builtin_amdgcn_global_load_lds(
                (const AS1 void*)(gP + (size_t)c * 16),
                (AS3 void*)((char*)&lds[wv][b][1][0] + k * 1024), 16, 0, 0);
        }
    };

    STAGE(0, 0);

    float acc = 0.0f;
#pragma unroll
    for (int p = 0; p < SPT; ++p) {
        const int site = tid + p * TSTRIDE;
        const int x = site >> 10, y = site & (LSZ - 1);
        const int xp = (x + 1) & (LSZ - 1), yp = (y + 1) & (LSZ - 1);
        // theta loads issued BEFORE next stage: queue = [stage_p(8), theta(~3),
        // stage_{p+1}(8)] -> vmcnt(8) drains stage_p + theta, keeps stage_{p+1}.
        const float3 a  = *(const float3*)(theta + 3 * (x  * LSZ + y));
        const float3 bt = *(const float3*)(theta + 3 * (xp * LSZ + y));
        const float3 ct = *(const float3*)(theta + 3 * (x  * LSZ + yp));
        __builtin_amdgcn_sched_barrier(0);

        if (p + 1 < SPT) STAGE(p + 1, (p + 1) & 1);
        __builtin_amdgcn_sched_barrier(0);
        if (p + 1 < SPT) asm volatile("s_waitcnt vmcnt(8)" ::: "memory");
        else             asm volatile("s_waitcnt vmcnt(0)" ::: "memory");
        __builtin_amdgcn_sched_barrier(0);

        // ---- swizzled LDS readback: 4x ds_read_b128 per array ----
        const float* lT = &lds[wv][p & 1][0][0];
        const float* lP = &lds[wv][p & 1][1][0];
        vfloat4 t[4], pr[4];
#pragma unroll
        for (int q = 0; q < 4; ++q) {
            const int c = 4 * lane + q;
            const int s = c ^ ((c >> 3) & 7);           // slot holding chunk c
            t[q]  = *(const vfloat4*)(lT + 4 * s);
            pr[q] = *(const vfloat4*)(lP + 4 * s);
        }

        c32 g[2][2], gn[2][2];
        make_g(a.x, a.y, a.z, g);
        make_g(bt.x, bt.y, bt.z, gn);
        acc += site_mu_loss(g, gn, t[0], t[1], pr[0], pr[1]);   // mu = 0
        make_g(ct.x, ct.y, ct.z, gn);
        acc += site_mu_loss(g, gn, t[2], t[3], pr[2], pr[3]);   // mu = 1
    }

    // fold: mean over 4 entries (1/4) and final /(L*L*2)
    acc *= (1.0f / (8.0f * (float)LSZ * (float)LSZ));

    // wave (64-lane) shuffle reduction
#pragma unroll
    for (int off = 32; off > 0; off >>= 1)
        acc += __shfl_down(acc, off, 64);

    __shared__ float wave_sums[4];
    if (lane == 0) wave_sums[wv] = acc;
    __syncthreads();
    if (threadIdx.x == 0)
        partial[blockIdx.x] = wave_sums[0] + wave_sums[1] + wave_sums[2] + wave_sums[3];
}

__global__ __launch_bounds__(256) void reduce_kernel(const float* __restrict__ partial,
                                                     float* __restrict__ out) {
    float s = 0.0f;
#pragma unroll
    for (int i = 0; i < NBLK / 256; ++i)
        s += partial[i * 256 + threadIdx.x];

#pragma unroll
    for (int off = 32; off > 0; off >>= 1)
        s += __shfl_down(s, off, 64);

    __shared__ float wave_sums[4];
    int lane = threadIdx.x & 63;
    int wave = threadIdx.x >> 6;
    if (lane == 0) wave_sums[wave] = s;
    __syncthreads();
    if (threadIdx.x == 0)
        out[0] = wave_sums[0] + wave_sums[1] + wave_sums[2] + wave_sums[3];
}

extern "C" void kernel_launch(void* const* d_in, const int* in_sizes, int n_in,
                              void* d_out, int out_size, void* d_ws, size_t ws_size,
                              hipStream_t stream) {
    const float* theta  = (const float*)d_in[0];
    const float* U_pred = (const float*)d_in[1];
    const float* U_true = (const float*)d_in[2];
    float* out = (float*)d_out;
    float* partial = (float*)d_ws;  // NBLK floats

    gauge_loss_kernel<<<NBLK, 256, 0, stream>>>(theta, U_pred, U_true, partial);
    reduce_kernel<<<1, 256, 0, stream>>>(partial, out);
}

// Round 8
// 147.913 us; speedup vs baseline: 1.2017x; 1.0774x over previous
//
#include <hip/hip_runtime.h>

#define LSZ 1024
#define EPS 1e-8f
#define NBLK 512
#define SPT 8                       // phases per thread; NBLK*256*SPT == L*L exactly
#define TSTRIDE (NBLK * 256)        // 131072 threads

// gfx950 CPol: bit0=sc0, bit1=nt, bit4=sc1. aux=2 -> `nt` flag, matching the
// policy __builtin_nontemporal_load emitted in R6 (proven correct + faster).
#define CPOL_NT 2

typedef float vfloat4 __attribute__((ext_vector_type(4)));

#define AS1 __attribute__((address_space(1)))
#define AS3 __attribute__((address_space(3)))

struct c32 { float re, im; };

__device__ __forceinline__ c32 cmul(c32 a, c32 b) {
    return { a.re * b.re - a.im * b.im, a.re * b.im + a.im * b.re };
}
// a * conj(b)
__device__ __forceinline__ c32 cmulc(c32 a, c32 b) {
    return { a.re * b.re + a.im * b.im, a.im * b.re - a.re * b.im };
}
__device__ __forceinline__ c32 cadd(c32 a, c32 b) {
    return { a.re + b.re, a.im + b.im };
}

// g = cos(n) I + i sinc(n) (theta . sigma). Native sin/cos/rcp: theta norms
// are <= ~7 (3 gaussians), safely in fast range; error ~1e-6 << 8e-2 thresh.
__device__ __forceinline__ void make_g(float tx, float ty, float tz, c32 g[2][2]) {
    float n2 = tx * tx + ty * ty + tz * tz;
    float n  = __builtin_amdgcn_sqrtf(n2);
    float cc = __cosf(n);
    float sn = __sinf(n);
    float s  = (n > EPS) ? (sn * __builtin_amdgcn_rcpf(n)) : 1.0f;
    float a1 = s * tx, a2 = s * ty, a3 = s * tz;
    g[0][0] = {  cc,  a3 };
    g[0][1] = {  a2,  a1 };
    g[1][0] = { -a2,  a1 };
    g[1][1] = {  cc, -a3 };
}

// Ut = g @ M @ gn^dagger ; return sum |P - Ut|^2 over the 4 entries
__device__ __forceinline__ float site_mu_loss(const c32 g[2][2], const c32 gn[2][2],
                                              vfloat4 m0, vfloat4 m1,
                                              vfloat4 p0, vfloat4 p1) {
    c32 M[2][2] = { { { m0.x, m0.y }, { m0.z, m0.w } },
                    { { m1.x, m1.y }, { m1.z, m1.w } } };
    c32 P[2][2] = { { { p0.x, p0.y }, { p0.z, p0.w } },
                    { { p1.x, p1.y }, { p1.z, p1.w } } };
    c32 T[2][2];
#pragma unroll
    for (int a = 0; a < 2; ++a)
#pragma unroll
        for (int cc = 0; cc < 2; ++cc)
            T[a][cc] = cadd(cmul(g[a][0], M[0][cc]), cmul(g[a][1], M[1][cc]));

    float acc = 0.0f;
#pragma unroll
    for (int a = 0; a < 2; ++a)
#pragma unroll
        for (int d = 0; d < 2; ++d) {
            c32 ut = cadd(cmulc(T[a][0], gn[d][0]), cmulc(T[a][1], gn[d][1]));
            float dr = P[a][d].re - ut.re;
            float di = P[a][d].im - ut.im;
            acc += dr * dr + di * di;
        }
    return acc;
}

// NT-DMA variant (R8). Eight rounds establish: duration == FETCH_SIZE /
// fetch-rate in every variant, and fetch-rate depends ONLY on cache policy:
//   temporal (any structure, any depth -- R7's 8KB/wave DMA included): 1.5 TB/s
//     (dirty-L3 victim handling after the harness's 268 MB poison fill)
//   nt (R6, but shallow -- VGPR=32, ~0.6 KB/wave in flight): 2.36 TB/s
// R7 = deep+temporal (policy-capped). R6 = NT+shallow (depth-capped: 0.6 KB
// x 14 waves/CU at 900ns is exactly ~2.4 TB/s). Untested combination: NT+deep.
// This kernel is R7 with aux=CPOL_NT on the global_load_lds (register-free
// depth, 8 KB/wave in flight) + NT theta loads. Tells: WRITE_SIZE ~0 (nt
// took), fetch-rate >=3.5 TB/s (depth was NT's limiter).
//
// gload_lds writes LINEAR (base + lane*16, rule #21), so the bank swizzle is
// applied on the GLOBAL source: involution f(c) = c ^ ((c>>3)&7) on 16B-chunk
// index. Writer lane l (instr k) fetches chunk 64k + f(l) -> slot 64k+l holds
// chunk f(64k+l). Reader (thread t, quarter q) wants chunk c=4t+q -> slot
// f(c). Read residues mod 8 are uniform (8 lanes/bank-quad = ds_read_b128
// conflict-free floor). Verified in R7 (absmax 0).
__global__ __launch_bounds__(256, 2) void gauge_loss_kernel(
    const float* __restrict__ theta,
    const float* __restrict__ U_pred,
    const float* __restrict__ U_true,
    float* __restrict__ partial) {
    // [wave][buf][arr: 0=U_true 1=U_pred][1024 floats = 4 KB]  -> 64 KB total
    __shared__ __align__(16) float lds[4][2][2][1024];
    const int tid  = blockIdx.x * 256 + threadIdx.x;
    const int lane = threadIdx.x & 63;
    const int wv   = threadIdx.x >> 6;
    const int lswz = lane ^ ((lane >> 3) & 7);          // writer-side source swizzle

    // ---- stage: issue 8 global_load_lds (4 KB U_true + 4 KB U_pred), NT ----
    auto STAGE = [&](int p, int b) {
        const size_t wbase = (size_t)(tid - lane) + (size_t)p * TSTRIDE;
        const char* gT = (const char*)U_true + wbase * 64;
        const char* gP = (const char*)U_pred + wbase * 64;
#pragma unroll
        for (int k = 0; k < 4; ++k) {
            const int c = k * 64 + lswz;                // chunk this lane fetches
            __builtin_amdgcn_global_load_lds(
                (const AS1 void*)(gT + (size_t)c * 16),
                (AS3 void*)((char*)&lds[wv][b][0][0] + k * 1024), 16, 0, CPOL_NT);
            __builtin_amdgcn_global_load_lds(
                (const AS1 void*)(gP + (size_t)c * 16),
                (AS3 void*)((char*)&lds[wv][b][1][0] + k * 1024), 16, 0, CPOL_NT);
        }
    };

    STAGE(0, 0);

    float acc = 0.0f;
#pragma unroll
    for (int p = 0; p < SPT; ++p) {
        const int site = tid + p * TSTRIDE;
        const int x = site >> 10, y = site & (LSZ - 1);
        const int xp = (x + 1) & (LSZ - 1), yp = (y + 1) & (LSZ - 1);
        // theta loads issued BEFORE next stage: queue = [stage_p(8), theta,
        // stage_{p+1}(8)] -> vmcnt(8) drains stage_p + theta, keeps stage_{p+1}.
        const float* ta = theta + 3 * (x  * LSZ + y);
        const float* tb = theta + 3 * (xp * LSZ + y);
        const float* tc = theta + 3 * (x  * LSZ + yp);
        float a0 = __builtin_nontemporal_load(ta);
        float a1 = __builtin_nontemporal_load(ta + 1);
        float a2 = __builtin_nontemporal_load(ta + 2);
        float b0 = __builtin_nontemporal_load(tb);
        float b1 = __builtin_nontemporal_load(tb + 1);
        float b2 = __builtin_nontemporal_load(tb + 2);
        float c0 = __builtin_nontemporal_load(tc);
        float c1 = __builtin_nontemporal_load(tc + 1);
        float c2 = __builtin_nontemporal_load(tc + 2);
        __builtin_amdgcn_sched_barrier(0);

        if (p + 1 < SPT) STAGE(p + 1, (p + 1) & 1);
        __builtin_amdgcn_sched_barrier(0);
        if (p + 1 < SPT) asm volatile("s_waitcnt vmcnt(8)" ::: "memory");
        else             asm volatile("s_waitcnt vmcnt(0)" ::: "memory");
        __builtin_amdgcn_sched_barrier(0);

        // ---- swizzled LDS readback: 4x ds_read_b128 per array ----
        const float* lT = &lds[wv][p & 1][0][0];
        const float* lP = &lds[wv][p & 1][1][0];
        vfloat4 t[4], pr[4];
#pragma unroll
        for (int q = 0; q < 4; ++q) {
            const int c = 4 * lane + q;
            const int s = c ^ ((c >> 3) & 7);           // slot holding chunk c
            t[q]  = *(const vfloat4*)(lT + 4 * s);
            pr[q] = *(const vfloat4*)(lP + 4 * s);
        }

        c32 g[2][2], gn[2][2];
        make_g(a0, a1, a2, g);
        make_g(b0, b1, b2, gn);
        acc += site_mu_loss(g, gn, t[0], t[1], pr[0], pr[1]);   // mu = 0
        make_g(c0, c1, c2, gn);
        acc += site_mu_loss(g, gn, t[2], t[3], pr[2], pr[3]);   // mu = 1
    }

    // fold: mean over 4 entries (1/4) and final /(L*L*2)
    acc *= (1.0f / (8.0f * (float)LSZ * (float)LSZ));

    // wave (64-lane) shuffle reduction
#pragma unroll
    for (int off = 32; off > 0; off >>= 1)
        acc += __shfl_down(acc, off, 64);

    __shared__ float wave_sums[4];
    if (lane == 0) wave_sums[wv] = acc;
    __syncthreads();
    if (threadIdx.x == 0)
        partial[blockIdx.x] = wave_sums[0] + wave_sums[1] + wave_sums[2] + wave_sums[3];
}

__global__ __launch_bounds__(256) void reduce_kernel(const float* __restrict__ partial,
                                                     float* __restrict__ out) {
    float s = 0.0f;
#pragma unroll
    for (int i = 0; i < NBLK / 256; ++i)
        s += partial[i * 256 + threadIdx.x];

#pragma unroll
    for (int off = 32; off > 0; off >>= 1)
        s += __shfl_down(s, off, 64);

    __shared__ float wave_sums[4];
    int lane = threadIdx.x & 63;
    int wave = threadIdx.x >> 6;
    if (lane == 0) wave_sums[wave] = s;
    __syncthreads();
    if (threadIdx.x == 0)
        out[0] = wave_sums[0] + wave_sums[1] + wave_sums[2] + wave_sums[3];
}

extern "C" void kernel_launch(void* const* d_in, const int* in_sizes, int n_in,
                              void* d_out, int out_size, void* d_ws, size_t ws_size,
                              hipStream_t stream) {
    const float* theta  = (const float*)d_in[0];
    const float* U_pred = (const float*)d_in[1];
    const float* U_true = (const float*)d_in[2];
    float* out = (float*)d_out;
    float* partial = (float*)d_ws;  // NBLK floats

    gauge_loss_kernel<<<NBLK, 256, 0, stream>>>(theta, U_pred, U_true, partial);
    reduce_kernel<<<1, 256, 0, stream>>>(partial, out);
}